// Round 7
// baseline (233.435 us; speedup 1.0000x reference)
//
#include <hip/hip_runtime.h>
#include <math.h>

// Problem constants
#define B_ 4
#define HH 64
#define WW 64
#define LL 4096          // H*W
#define DM 96            // d_model
#define DI 192           // d_inner
#define NS 16            // n_state
#define RR 6             // r_rank
#define KK 4             // directions
#define NROW (B_ * KK * DI)   // 3072 scan rows
#define XPS 160          // xdblP row stride per pixel (4 dirs x 40)
#define KOFF 40          // per-direction block within a row (38 real + 2 pad)

__device__ __forceinline__ int pix_of(int k, int l) {
    switch (k) {
        case 0: return l;
        case 1: { int w = l >> 6, h = l & 63; return (h << 6) + w; }
        case 2: return (LL - 1) - l;
        default: { int ll = (LL - 1) - l; int w = ll >> 6, h = ll & 63; return (h << 6) + w; }
    }
}

// Fast math (native v_exp_f32 / v_log_f32 / v_rcp_f32)
__device__ __forceinline__ float silu_f(float v) {
    return v * __fdividef(1.f, 1.f + __expf(-v));
}

// ---------------- GEMM: C[M,N] = A[M,K] * Bw[N,K]^T ----------------
// Transposed LDS tiles (k-major): inner loop = 2x ds_read_b128 + 16 FMA.
// MODE 0: in_proj epilogue (n<192 -> C0 raw; else silu -> C1)
// MODE 1: plain store C0[M,N]
// MODE 2: xdbl epilogue: n<152 -> C0[m*160 + (n/38)*40 + n%38]
template<int MODE>
__global__ __launch_bounds__(256)
void gemm_kernel(const float* __restrict__ A, const float* __restrict__ Bw,
                 float* __restrict__ C0, float* __restrict__ C1,
                 int M, int N, int Kd) {
    __shared__ float As[32][68];   // [k][m] ; 68*4B = 17*16B -> b128-aligned rows
    __shared__ float Bs[32][68];   // [k][n]
    int tid = threadIdx.x;
    int tx = tid & 15, ty = tid >> 4;
    int m0 = blockIdx.y * 64, n0 = blockIdx.x * 64;
    float acc[4][4] = {};
    for (int k0 = 0; k0 < Kd; k0 += 32) {
        #pragma unroll
        for (int i = 0; i < 8; ++i) {
            int idx = tid + i * 256;
            int r = idx >> 5, c = idx & 31;
            As[c][r] = A[(size_t)(m0 + r) * Kd + k0 + c];
            int rn = n0 + r;
            Bs[c][r] = (rn < N) ? Bw[(size_t)rn * Kd + k0 + c] : 0.f;
        }
        __syncthreads();
        #pragma unroll
        for (int kk = 0; kk < 32; ++kk) {
            float4 av = *(const float4*)&As[kk][ty * 4];
            float4 bv = *(const float4*)&Bs[kk][tx * 4];
            const float* avp = (const float*)&av;
            const float* bvp = (const float*)&bv;
            #pragma unroll
            for (int i = 0; i < 4; ++i)
                #pragma unroll
                for (int j = 0; j < 4; ++j)
                    acc[i][j] += avp[i] * bvp[j];
        }
        __syncthreads();
    }
    #pragma unroll
    for (int i = 0; i < 4; ++i) {
        int m = m0 + ty * 4 + i;
        #pragma unroll
        for (int j = 0; j < 4; ++j) {
            int n = n0 + tx * 4 + j;
            if (n >= N) continue;
            float v = acc[i][j];
            if (MODE == 0) {
                if (n < DI) C0[(size_t)m * DI + n] = v;
                else        C1[(size_t)m * DI + (n - DI)] = silu_f(v);
            } else if (MODE == 1) {
                C0[(size_t)m * N + n] = v;
            } else {
                if (n < 152) {
                    int kd = n / 38, c = n - kd * 38;
                    C0[(size_t)m * XPS + kd * KOFF + c] = v;
                }
            }
        }
    }
}

// ---------------- Depthwise 3x3 conv + bias + SiLU, 8-pixel row tile ----------------
__global__ __launch_bounds__(192)
void conv_kernel(const float* __restrict__ xc, const float* __restrict__ cw,
                 const float* __restrict__ cb, float* __restrict__ out) {
    int p0 = blockIdx.x * 8;     // 8 pixels, same row (8 | 64)
    int b = blockIdx.y;
    int c = threadIdx.x;
    int h = p0 >> 6, w0 = p0 & 63;
    float kw[9];
    #pragma unroll
    for (int j = 0; j < 9; ++j) kw[j] = cw[c * 9 + j];
    float xv[3][10];
    #pragma unroll
    for (int dh = 0; dh < 3; ++dh) {
        int hh = h + dh - 1;
        bool hv = (hh >= 0 && hh < HH);
        #pragma unroll
        for (int j = 0; j < 10; ++j) {
            int ww = w0 + j - 1;
            bool v = hv && (ww >= 0 && ww < WW);
            xv[dh][j] = v ? xc[((size_t)(b << 12) + (hh << 6) + ww) * DI + c] : 0.f;
        }
    }
    float bias = cb[c];
    #pragma unroll
    for (int w = 0; w < 8; ++w) {
        float acc = bias;
        #pragma unroll
        for (int dh = 0; dh < 3; ++dh)
            #pragma unroll
            for (int dc = 0; dc < 3; ++dc)
                acc += xv[dh][w + dc] * kw[dh * 3 + dc];
        out[((size_t)(b << 12) + p0 + w) * DI + c] = silu_f(acc);
    }
}

// ---------------- Scan phases ----------------
// Block = 192 threads (3 waves), one d per thread, one (b,k,chunk) per block.
// xdblP layout: [b*4096+p][160], direction k's 38 values at offset k*40.
// carryB layout: [chunk][row][n]; sumD layout: [chunk][row]; row = (b*K+k)*DI+d
// Within an aligned chunk (CHL<=32, l0%32==0): pixel p = p0 + i*s, s in {1,64,-1,-64}.
template<int PHASE, int NCHT>
__global__ __launch_bounds__(192)
void scan_phase(const float* __restrict__ xconv, const float* __restrict__ xdblP,
                const float* __restrict__ dtw, const float* __restrict__ dtb,
                const float* __restrict__ A_logs, const float* __restrict__ Ds,
                float* __restrict__ sumD, float* __restrict__ carryB,
                float* __restrict__ y_acc) {
    constexpr int CHL = LL / NCHT;
    constexpr int NV4 = (PHASE == 3) ? (KOFF / 4) : 6;   // float4s staged per step
    int chunk = blockIdx.x;
    int k = blockIdx.y;
    int b = blockIdx.z;
    int d = threadIdx.x;
    int l0 = chunk * CHL;
    __shared__ float sx[CHL * NV4 * 4];
    float4* sx4 = (float4*)sx;
    const float* xb = xdblP + ((size_t)(b << 12)) * XPS + k * KOFF;
    for (int idx = d; idx < CHL * NV4; idx += DI) {
        int r = idx / NV4, j = idx - r * NV4;
        int p = pix_of(k, l0 + r);
        sx4[idx] = *(const float4*)(xb + (size_t)p * XPS + j * 4);
    }

    float wr[RR];
    #pragma unroll
    for (int r = 0; r < RR; ++r) wr[r] = dtw[(k * DI + d) * RR + r];
    float bias = dtb[k * DI + d];
    const float* alog = A_logs + (size_t)(k * DI + d) * NS;
    // Check An[n] == -(n+1) (holds for A = arange(1..16); 100x ulp tolerance)
    bool fastA = true;
    #pragma unroll
    for (int n = 0; n < NS; ++n) {
        float an = -__expf(alog[n]);
        fastA = fastA && (fabsf(an + (float)(n + 1)) < 1e-4f * (float)(n + 1));
    }
    float h[NS];
    int row = (b * KK + k) * DI + d;
    if (PHASE == 1) {
        #pragma unroll
        for (int n = 0; n < NS; ++n) h[n] = 0.f;
    } else {
        const float4* cb4 = (const float4*)(carryB + ((size_t)chunk * NROW + row) * NS);
        #pragma unroll
        for (int q = 0; q < NS / 4; ++q) {
            float4 v = cb4[q];
            h[q * 4 + 0] = v.x; h[q * 4 + 1] = v.y;
            h[q * 4 + 2] = v.z; h[q * 4 + 3] = v.w;
        }
    }
    float Dk = (PHASE == 3) ? Ds[k * DI + d] : 0.f;
    float sumDelta = 0.f;
    __syncthreads();

    // affine pixel walk
    int s = (k == 0) ? 1 : (k == 1) ? 64 : (k == 2) ? -1 : -64;
    int p0 = pix_of(k, l0);
    intptr_t stp = (intptr_t)s * DI;
    const float* up = xconv + (size_t)(b << 12) * DI + (size_t)p0 * DI + d;
    float* yp = y_acc + (size_t)(b << 12) * DI + (size_t)p0 * DI + d;
    float u_cur = *up;

    for (int i = 0; i < CHL; ++i) {
        float u_nxt = *(up + stp);   // one-past-end read on last iter lands in ws (safe, unused)
        float xrv[NV4 * 4];
        float4* x4 = (float4*)xrv;
        #pragma unroll
        for (int j = 0; j < NV4; ++j) x4[j] = sx4[i * NV4 + j];
        float dtraw = bias;
        #pragma unroll
        for (int r = 0; r < RR; ++r) dtraw += xrv[r] * wr[r];
        // softplus + decay base: g = exp(-softplus(x)) == 1/(1+e^x)  (rcp path, no log dep)
        float e = __expf(dtraw);
        float g = __fdividef(1.f, 1.f + e);
        float delta = (dtraw > 20.f) ? dtraw : __logf(1.f + e);
        if (PHASE == 1) sumDelta += delta;
        float du = delta * u_cur;
        float y;
        if (fastA) {
            // a[n] = g^(n+1), binary-power tree (depth 4)
            float a[NS];
            a[0] = g;          a[1] = g * g;      a[2] = a[1] * g;    a[3] = a[1] * a[1];
            a[4] = a[3] * g;   a[5] = a[3] * a[1]; a[6] = a[3] * a[2]; a[7] = a[3] * a[3];
            a[8] = a[7] * g;   a[9] = a[7] * a[1]; a[10] = a[7] * a[2]; a[11] = a[7] * a[3];
            a[12] = a[7] * a[4]; a[13] = a[7] * a[5]; a[14] = a[7] * a[6]; a[15] = a[7] * a[7];
            float yp4[4] = {0.f, 0.f, 0.f, 0.f};
            #pragma unroll
            for (int n = 0; n < NS; ++n) {
                h[n] = a[n] * h[n] + du * xrv[6 + n];
                if (PHASE == 3) yp4[n & 3] += h[n] * xrv[22 + n];
            }
            y = (yp4[0] + yp4[1]) + (yp4[2] + yp4[3]);
        } else {
            y = 0.f;
            #pragma unroll
            for (int n = 0; n < NS; ++n) {
                float a = __expf(delta * (-__expf(alog[n])));
                h[n] = a * h[n] + du * xrv[6 + n];
                if (PHASE == 3) y += h[n] * xrv[22 + n];
            }
        }
        if (PHASE == 3) {
            y += u_cur * Dk;
            atomicAdd(yp, y);
            yp += stp;
        }
        up += stp;
        u_cur = u_nxt;
    }
    if (PHASE == 1) {
        float4* cb4 = (float4*)(carryB + ((size_t)chunk * NROW + row) * NS);
        #pragma unroll
        for (int q = 0; q < NS / 4; ++q) {
            float4 vb;
            vb.x = h[q * 4 + 0]; vb.y = h[q * 4 + 1];
            vb.z = h[q * 4 + 2]; vb.w = h[q * 4 + 3];
            cb4[q] = vb;
        }
        sumD[(size_t)chunk * NROW + row] = sumDelta;
    }
}

// ---------------- Phase 2: sequential scan over chunk carries ----------------
// a(chunk) reconstructed exactly: prod_i exp(An*d_i) == exp(An * sum d_i)
template<int NCHT>
__global__ __launch_bounds__(256)
void scan_chunks(const float* __restrict__ sumD, const float* __restrict__ A_logs,
                 float* __restrict__ carryB) {
    int t = blockIdx.x * 256 + threadIdx.x;
    if (t >= NROW * NS) return;
    int row = t >> 4, n = t & 15;
    int kd = row % (KK * DI);
    float An = -__expf(A_logs[(size_t)kd * NS + n]);
    float h = 0.f;
    for (int c = 0; c < NCHT; ++c) {
        size_t idx = (size_t)c * (NROW * NS) + t;
        float bb = carryB[idx];
        carryB[idx] = h;       // exclusive prefix = h_in for chunk c
        float a = __expf(An * sumD[(size_t)c * NROW + row]);
        h = a * h + bb;
    }
}

// ---------------- LayerNorm * z ----------------
__global__ __launch_bounds__(256)
void ln_kernel(const float* __restrict__ y_acc, const float* __restrict__ z_silu,
               const float* __restrict__ nw, const float* __restrict__ nb,
               float* __restrict__ out) {
    int pg = blockIdx.x * 4 + (threadIdx.x >> 6);
    int lane = threadIdx.x & 63;
    const float* yr = y_acc + (size_t)pg * DI;
    float v0 = yr[lane], v1 = yr[lane + 64], v2 = yr[lane + 128];
    float s = v0 + v1 + v2;
    float sq = v0 * v0 + v1 * v1 + v2 * v2;
    #pragma unroll
    for (int m = 32; m >= 1; m >>= 1) {
        s  += __shfl_xor(s, m, 64);
        sq += __shfl_xor(sq, m, 64);
    }
    float mu = s * (1.f / 192.f);
    float var = sq * (1.f / 192.f) - mu * mu;
    float rs = rsqrtf(var + 1e-5f);
    const float* zr = z_silu + (size_t)pg * DI;
    float* o = out + (size_t)pg * DI;
    float vv[3] = {v0, v1, v2};
    #pragma unroll
    for (int j = 0; j < 3; ++j) {
        int c = lane + j * 64;
        o[c] = (nw[c] * (vv[j] - mu) * rs + nb[c]) * zr[c];
    }
}

extern "C" void kernel_launch(void* const* d_in, const int* in_sizes, int n_in,
                              void* d_out, int out_size, void* d_ws, size_t ws_size,
                              hipStream_t stream) {
    const float* x        = (const float*)d_in[0];
    const float* in_projw = (const float*)d_in[1];
    const float* conv_w   = (const float*)d_in[2];
    const float* conv_b   = (const float*)d_in[3];
    const float* x_projw  = (const float*)d_in[4];
    const float* dt_w     = (const float*)d_in[5];
    const float* dt_b     = (const float*)d_in[6];
    const float* A_logs   = (const float*)d_in[7];
    const float* Ds       = (const float*)d_in[8];
    const float* nw       = (const float*)d_in[9];
    const float* nb       = (const float*)d_in[10];
    const float* opw      = (const float*)d_in[11];
    float* out = (float*)d_out;
    float* ws = (float*)d_ws;

    const size_t SZ = (size_t)B_ * LL * DI;          // 3,145,728
    const size_t XD = (size_t)B_ * LL * XPS;         // 2,621,440
    const size_t CAR = (size_t)NROW * 128 * NS;      // 6,291,456

    float* z_silu = ws;
    float* xc_raw = ws + SZ;            // reused as y_acc
    float* xconv  = ws + 2 * SZ;        // reused as yln after phase 3
    float* xdblP  = ws + 3 * SZ;
    float* carryB = ws + 3 * SZ + XD;
    float* sumD   = carryB + CAR;
    float* y_acc  = xc_raw;
    float* yln    = xconv;

    gemm_kernel<0><<<dim3(6, 256), 256, 0, stream>>>(x, in_projw, xc_raw, z_silu,
                                                     B_ * LL, 2 * DI, DM);
    conv_kernel<<<dim3(LL / 8, B_), DI, 0, stream>>>(xc_raw, conv_w, conv_b, xconv);
    // x_dbl for all 4 directions in one pixel-order GEMM (152 = 4*38 outputs)
    gemm_kernel<2><<<dim3(3, 256), 256, 0, stream>>>(xconv, x_projw, xdblP, nullptr,
                                                     B_ * LL, 152, DI);

    scan_phase<1, 128><<<dim3(128, KK, B_), DI, 0, stream>>>(xconv, xdblP, dt_w, dt_b,
                                                             A_logs, Ds, sumD, carryB, nullptr);
    scan_chunks<128><<<(NROW * NS + 255) / 256, 256, 0, stream>>>(sumD, A_logs, carryB);
    hipMemsetAsync(y_acc, 0, SZ * sizeof(float), stream);
    scan_phase<3, 128><<<dim3(128, KK, B_), DI, 0, stream>>>(xconv, xdblP, dt_w, dt_b,
                                                             A_logs, Ds, sumD, carryB, y_acc);

    ln_kernel<<<(B_ * LL) / 4, 256, 0, stream>>>(y_acc, z_silu, nw, nb, yln);
    gemm_kernel<1><<<dim3(2, 256), 256, 0, stream>>>(yln, opw, out, nullptr,
                                                     B_ * LL, DM, DI);
}